// Round 10
// baseline (222.827 us; speedup 1.0000x reference)
//
#include <hip/hip_runtime.h>
#include <math.h>

#define N_NODES 25000
#define N_EDGES 400000
#define EMBED   128
#define HEADS   8
#define DK      16
#define NBLK    98        // ceil(25000/256)
#define GQB     1563      // ceil(25000/16)

typedef __attribute__((ext_vector_type(8))) short bf16x8;
typedef __attribute__((ext_vector_type(4))) float f32x4;
typedef unsigned int uint;
typedef unsigned short ushort;

__device__ inline uint pack2_bf16(float a, float b) {
    union { float f; uint u; } ua, ub;
    ua.f = a; ub.f = b;
    uint ra = (ua.u + 0x7FFFu + ((ua.u >> 16) & 1u)) >> 16;
    uint rb = (ub.u + 0x7FFFu + ((ub.u >> 16) & 1u)) >> 16;
    return (ra & 0xFFFFu) | (rb << 16);
}
__device__ inline ushort cvt_bf16(float a) {
    union { float f; uint u; } ua; ua.f = a;
    return (ushort)((ua.u + 0x7FFFu + ((ua.u >> 16) & 1u)) >> 16);
}
__device__ inline float bf16_lo(uint u) {
    union { uint u; float f; } x; x.u = u << 16; return x.f;
}
__device__ inline float bf16_hi(uint u) {
    union { uint u; float f; } x; x.u = u & 0xFFFF0000u; return x.f;
}

// ---------------------------------------------------------------------------
// Convert x (N*128) and the four 128x128 weights to bf16; zero deg inline.
// ---------------------------------------------------------------------------
#define NX (N_NODES * 128)
__global__ __launch_bounds__(256) void convert_all(
    const float* __restrict__ x,
    const float* __restrict__ Wq, const float* __restrict__ Wk,
    const float* __restrict__ Wv, const float* __restrict__ Wo,
    ushort* __restrict__ xb, ushort* __restrict__ wb, int* __restrict__ deg)
{
    int i = blockIdx.x * 256 + threadIdx.x;   // pair index
    if (i < N_NODES) deg[i] = 0;
    int base = i * 2;
    if (base < NX) {
        float2 v = *reinterpret_cast<const float2*>(x + base);
        reinterpret_cast<uint*>(xb)[i] = pack2_bf16(v.x, v.y);
    } else {
        int j = base - NX;
        if (j < 4 * 16384) {
            const float* src = (j < 16384) ? Wq + j
                             : (j < 32768) ? Wk + (j - 16384)
                             : (j < 49152) ? Wv + (j - 32768)
                             :               Wo + (j - 49152);
            float2 v = *reinterpret_cast<const float2*>(src);
            reinterpret_cast<uint*>(wb)[j >> 1] = pack2_bf16(v.x, v.y);
        }
    }
}

// ---------------------------------------------------------------------------
// ONE-PASS Q/K/V GEMM + histogram. blockIdx.y==0: one WAVE (64 threads) per
// 16 rows computes Q,K,V together: 24 independent MFMA accumulator chains
// (8 col-tiles x 3 matrices) -> deep ILP; A read once. blockIdx.y==1:
// degree histogram. W (96 KB bf16) is L2-resident.
// ---------------------------------------------------------------------------
__global__ __launch_bounds__(64) void gemm_qkv3(
    const ushort* __restrict__ A, const ushort* __restrict__ Wall,
    const float* __restrict__ bq, const float* __restrict__ bk,
    const float* __restrict__ bv,
    ushort* __restrict__ Qb, ushort* __restrict__ Kb, ushort* __restrict__ Vb,
    const int* __restrict__ ei, int* __restrict__ deg,
    int M)
{
    if (blockIdx.y == 1) {
        int t = blockIdx.x * 64 + threadIdx.x;
        int e = t * 4;
        if (e + 3 < N_EDGES) {
            int4 d = *reinterpret_cast<const int4*>(ei + e);
            atomicAdd(&deg[d.x], 1);
            atomicAdd(&deg[d.y], 1);
            atomicAdd(&deg[d.z], 1);
            atomicAdd(&deg[d.w], 1);
        } else {
            for (; e < N_EDGES && e < t * 4 + 4; ++e)
                atomicAdd(&deg[ei[e]], 1);
        }
        return;
    }

    const int lane = threadIdx.x;
    const int ml   = lane & 15;
    const int quad = lane >> 4;
    const int m0   = blockIdx.x * 16;

    int arow = m0 + ml; if (arow >= M) arow = M - 1;
    const ushort* ap = A + arow * 128 + quad * 8;

    f32x4 acc[24];
#pragma unroll
    for (int i = 0; i < 24; ++i) acc[i] = (f32x4){0.f, 0.f, 0.f, 0.f};

#pragma unroll
    for (int ks = 0; ks < 128; ks += 32) {
        bf16x8 af = *reinterpret_cast<const bf16x8*>(ap + ks);
#pragma unroll
        for (int w = 0; w < 3; ++w) {
#pragma unroll
            for (int ct = 0; ct < 8; ++ct) {
                bf16x8 bf = *reinterpret_cast<const bf16x8*>(
                    Wall + w * 16384 + (ct * 16 + ml) * 128 + ks + quad * 8);
                acc[w * 8 + ct] =
                    __builtin_amdgcn_mfma_f32_16x16x32_bf16(af, bf, acc[w * 8 + ct], 0, 0, 0);
            }
        }
    }

#pragma unroll
    for (int w = 0; w < 3; ++w) {
        ushort* C = (w == 0) ? Qb : (w == 1) ? Kb : Vb;
        const float* bias = (w == 0) ? bq : (w == 1) ? bk : bv;
#pragma unroll
        for (int ct = 0; ct < 8; ++ct) {
            int col = ct * 16 + ml;
            float bv_ = bias[col];
#pragma unroll
            for (int r = 0; r < 4; ++r) {
                int row = m0 + quad * 4 + r;
                if (row < M)
                    C[row * 128 + col] = cvt_bf16(acc[w * 8 + ct][r] + bv_);
            }
        }
    }
}

// Final projection: A bf16 [M,128] @ W^T + bias -> fp32 out
__global__ __launch_bounds__(256) void gemm_out(
    const ushort* __restrict__ A, const ushort* __restrict__ W,
    const float* __restrict__ bias, float* __restrict__ C, int M)
{
    const int lane = threadIdx.x & 63;
    const int wave = threadIdx.x >> 6;
    const int ml   = lane & 15;
    const int quad = lane >> 4;
    const int m0   = blockIdx.x * 64 + wave * 16;

    int arow = m0 + ml; if (arow >= M) arow = M - 1;
    const ushort* ap = A + arow * 128 + quad * 8;

    f32x4 acc[8];
#pragma unroll
    for (int ct = 0; ct < 8; ++ct) acc[ct] = (f32x4){0.f, 0.f, 0.f, 0.f};

#pragma unroll
    for (int ks = 0; ks < 128; ks += 32) {
        bf16x8 af = *reinterpret_cast<const bf16x8*>(ap + ks);
#pragma unroll
        for (int ct = 0; ct < 8; ++ct) {
            bf16x8 bf = *reinterpret_cast<const bf16x8*>(
                W + (ct * 16 + ml) * 128 + ks + quad * 8);
            acc[ct] = __builtin_amdgcn_mfma_f32_16x16x32_bf16(af, bf, acc[ct], 0, 0, 0);
        }
    }

#pragma unroll
    for (int ct = 0; ct < 8; ++ct) {
        int col = ct * 16 + ml;
        float bv_ = bias[col];
#pragma unroll
        for (int r = 0; r < 4; ++r) {
            int row = m0 + quad * 4 + r;
            if (row < M)
                C[row * 128 + col] = acc[ct][r] + bv_;
        }
    }
}

// ---------------------------------------------------------------------------
// Hierarchical exclusive scan (2 kernels) + scatter (int2 {e, src}).
// ---------------------------------------------------------------------------
__global__ __launch_bounds__(256) void scan_blocks(
    const int* __restrict__ deg, int* __restrict__ excl, int* __restrict__ bsum)
{
    __shared__ int sh[256];
    int t = threadIdx.x;
    int gid = blockIdx.x * 256 + t;
    int v = (gid < N_NODES) ? deg[gid] : 0;
    sh[t] = v;
    __syncthreads();
#pragma unroll
    for (int off = 1; off < 256; off <<= 1) {
        int u = (t >= off) ? sh[t - off] : 0;
        __syncthreads();
        sh[t] += u;
        __syncthreads();
    }
    if (gid < N_NODES) excl[gid] = sh[t] - v;
    if (t == 255) bsum[blockIdx.x] = sh[255];
}

__global__ __launch_bounds__(256) void scan_apply(
    int* __restrict__ excl, const int* __restrict__ bsum,
    int* __restrict__ cursor)
{
    __shared__ int base_sh;
    int t = threadIdx.x;
    if (t < 64) {
        int s = 0;
        for (int i = t; i < (int)blockIdx.x; i += 64) s += bsum[i];
#pragma unroll
        for (int off = 32; off; off >>= 1) s += __shfl_xor(s, off, 64);
        if (t == 0) base_sh = s;
    }
    __syncthreads();
    int gid = blockIdx.x * 256 + t;
    if (gid < N_NODES) {
        int o = excl[gid] + base_sh;
        excl[gid] = o;         // excl buffer IS offsets
        cursor[gid] = o;
    }
    if (blockIdx.x == 0 && t == 0) excl[N_NODES] = N_EDGES;
}

__global__ __launch_bounds__(256) void scatter_edges(
    const int* __restrict__ ei, int* __restrict__ cursor,
    int2* __restrict__ csr2)
{
    int e = blockIdx.x * 256 + threadIdx.x;
    if (e >= N_EDGES) return;
    int dst = ei[e];
    int src = ei[N_EDGES + e];
    int pos = atomicAdd(&cursor[dst], 1);
    csr2[pos] = make_int2(e, src);
}

// ---------------------------------------------------------------------------
// Fused attention v7 (r8-proven): one wave per node, one (edge, head) per
// lane. lane = e_slot*8 + h. Full 16-dim dot in registers; exp once per
// (e,h); reduce-scatter butterfly at the end. exp without max-subtraction.
// ---------------------------------------------------------------------------
__global__ __launch_bounds__(256) void fused_attn(
    const ushort* __restrict__ Q2, const ushort* __restrict__ K2,
    const ushort* __restrict__ V2,
    const float* __restrict__ attn_bias,
    const int* __restrict__ offsets, const int2* __restrict__ csr2,
    float* __restrict__ logits, ushort* __restrict__ AGG)
{
    const int lane = threadIdx.x & 63;
    const int wid  = threadIdx.x >> 6;
    const int n = blockIdx.x * 4 + wid;
    const int start = offsets[n], end = offsets[n + 1];
    const int h  = lane & 7;
    const int es = lane >> 3;

    const uint4* Qu4 = reinterpret_cast<const uint4*>(Q2);
    const uint4* Ku4 = reinterpret_cast<const uint4*>(K2);
    const uint4* Vu4 = reinterpret_cast<const uint4*>(V2);

    uint4 qa = Qu4[n * 16 + h * 2];
    uint4 qb = Qu4[n * 16 + h * 2 + 1];
    float qf[16];
    {
        uint qq[8] = {qa.x, qa.y, qa.z, qa.w, qb.x, qb.y, qb.z, qb.w};
#pragma unroll
        for (int j = 0; j < 8; ++j) {
            qf[2 * j]     = bf16_lo(qq[j]);
            qf[2 * j + 1] = bf16_hi(qq[j]);
        }
    }

    float acc[16];
#pragma unroll
    for (int j = 0; j < 16; ++j) acc[j] = 0.f;
    float z = 0.f;

    for (int base = start; base < end; base += 8) {
        bool valid = (base + es) < end;
        int idx = base + es; if (!valid) idx = end - 1;
        int2 epair = csr2[idx];
        int e = epair.x, s = epair.y;

        uint4 k0 = Ku4[s * 16 + h * 2];
        uint4 k1 = Ku4[s * 16 + h * 2 + 1];
        uint4 v0 = Vu4[s * 16 + h * 2];
        uint4 v1 = Vu4[s * 16 + h * 2 + 1];
        float bias = attn_bias[e * 8 + h];

        uint kk[8] = {k0.x, k0.y, k0.z, k0.w, k1.x, k1.y, k1.z, k1.w};
        float d = 0.f;
#pragma unroll
        for (int j = 0; j < 8; ++j)
            d += qf[2 * j] * bf16_lo(kk[j]) + qf[2 * j + 1] * bf16_hi(kk[j]);

        float l = 0.25f * d + bias;
        float p = 0.f;
        if (valid) {
            logits[e * 8 + h] = l;
            p = __expf(l);
        }
        z += p;

        uint vv[8] = {v0.x, v0.y, v0.z, v0.w, v1.x, v1.y, v1.z, v1.w};
#pragma unroll
        for (int j = 0; j < 8; ++j) {
            acc[2 * j]     += p * bf16_lo(vv[j]);
            acc[2 * j + 1] += p * bf16_hi(vv[j]);
        }
    }

    // reduce-scatter butterfly over e_slot bits (lane bits 5,4,3)
    {
        int bit = (lane >> 5) & 1;
#pragma unroll
        for (int j = 0; j < 8; ++j) {
            float send = bit ? acc[j] : acc[j + 8];
            float keep = bit ? acc[j + 8] : acc[j];
            acc[j] = keep + __shfl_xor(send, 32, 64);
        }
        bit = (lane >> 4) & 1;
#pragma unroll
        for (int j = 0; j < 4; ++j) {
            float send = bit ? acc[j] : acc[j + 4];
            float keep = bit ? acc[j + 4] : acc[j];
            acc[j] = keep + __shfl_xor(send, 16, 64);
        }
        bit = (lane >> 3) & 1;
#pragma unroll
        for (int j = 0; j < 2; ++j) {
            float send = bit ? acc[j] : acc[j + 2];
            float keep = bit ? acc[j + 2] : acc[j];
            acc[j] = keep + __shfl_xor(send, 8, 64);
        }
    }
    z += __shfl_xor(z, 8, 64);
    z += __shfl_xor(z, 16, 64);
    z += __shfl_xor(z, 32, 64);

    float inv = (z > 0.f) ? 1.f / z : 0.f;
    int d_off = ((lane >> 5) & 1) * 8 + ((lane >> 4) & 1) * 4 + ((lane >> 3) & 1) * 2;
    reinterpret_cast<uint*>(AGG)[n * 64 + h * 8 + (d_off >> 1)] =
        pack2_bf16(acc[0] * inv, acc[1] * inv);
}

// ---------------------------------------------------------------------------
extern "C" void kernel_launch(void* const* d_in, const int* in_sizes, int n_in,
                              void* d_out, int out_size, void* d_ws, size_t ws_size,
                              hipStream_t stream)
{
    const float* x         = (const float*)d_in[0];
    const int*   ei        = (const int*)  d_in[1];
    const float* attn_bias = (const float*)d_in[2];
    const float* Wq = (const float*)d_in[3];
    const float* bq = (const float*)d_in[4];
    const float* Wk = (const float*)d_in[5];
    const float* bk = (const float*)d_in[6];
    const float* Wv = (const float*)d_in[7];
    const float* bv = (const float*)d_in[8];
    const float* Wo = (const float*)d_in[9];
    const float* bo = (const float*)d_in[10];

    float* out    = (float*)d_out;                // [N,128]
    float* logits = out + N_NODES * EMBED;        // [E,8] (output 1)

    ushort* xb   = (ushort*)d_ws;                 // N*128
    ushort* wb   = xb + NX;                       // 4*16384 (Wq,Wk,Wv,Wo)
    ushort* Qb   = wb + 4 * 16384;                // N*128
    ushort* Kb   = Qb + NX;                       // N*128
    ushort* Vb   = Kb + NX;                       // N*128
    ushort* AGGb = Vb + NX;                       // N*128
    int* deg     = (int*)(AGGb + NX);
    int* offsets = deg + N_NODES;                 // N+1 (also excl buffer)
    int* cursor  = offsets + N_NODES + 1;
    int2* csr2   = (int2*)(cursor + N_NODES);     // E pairs {edge, src}
    int* bsum    = (int*)(csr2 + N_EDGES);        // NBLK

    int npairs = (NX + 4 * 16384) / 2;
    convert_all<<<(npairs + 255) / 256, 256, 0, stream>>>(x, Wq, Wk, Wv, Wo, xb, wb, deg);

    dim3 qkvgrid(GQB, 2);                         // y=0 QKV gemm, y=1 histogram
    gemm_qkv3<<<qkvgrid, 64, 0, stream>>>(xb, wb, bq, bk, bv, Qb, Kb, Vb,
                                          ei, deg, N_NODES);

    scan_blocks<<<NBLK, 256, 0, stream>>>(deg, offsets, bsum);
    scan_apply<<<NBLK, 256, 0, stream>>>(offsets, bsum, cursor);
    scatter_edges<<<(N_EDGES + 255) / 256, 256, 0, stream>>>(ei, cursor, csr2);

    fused_attn<<<N_NODES / 4, 256, 0, stream>>>(Qb, Kb, Vb, attn_bias,
                                                offsets, csr2, logits, AGGb);

    int gblocks = (N_NODES + 63) / 64;            // 391
    gemm_out<<<gblocks, 256, 0, stream>>>(AGGb, wb + 3 * 16384, bo, out, N_NODES);
}

// Round 11
// 211.123 us; speedup vs baseline: 1.0554x; 1.0554x over previous
//
#include <hip/hip_runtime.h>
#include <math.h>

#define N_NODES 25000
#define N_EDGES 400000
#define EMBED   128
#define HEADS   8
#define DK      16
#define NBLK    98        // ceil(25000/256)

typedef __attribute__((ext_vector_type(8))) short bf16x8;
typedef __attribute__((ext_vector_type(4))) float f32x4;
typedef unsigned int uint;
typedef unsigned short ushort;

__device__ inline uint pack2_bf16(float a, float b) {
    union { float f; uint u; } ua, ub;
    ua.f = a; ub.f = b;
    uint ra = (ua.u + 0x7FFFu + ((ua.u >> 16) & 1u)) >> 16;
    uint rb = (ub.u + 0x7FFFu + ((ub.u >> 16) & 1u)) >> 16;
    return (ra & 0xFFFFu) | (rb << 16);
}
__device__ inline ushort cvt_bf16(float a) {
    union { float f; uint u; } ua; ua.f = a;
    return (ushort)((ua.u + 0x7FFFu + ((ua.u >> 16) & 1u)) >> 16);
}
__device__ inline float bf16_lo(uint u) {
    union { uint u; float f; } x; x.u = u << 16; return x.f;
}
__device__ inline float bf16_hi(uint u) {
    union { uint u; float f; } x; x.u = u & 0xFFFF0000u; return x.f;
}

// ---------------------------------------------------------------------------
// Convert x (N*128) and the four 128x128 weights to bf16; zero deg inline.
// ---------------------------------------------------------------------------
#define NX (N_NODES * 128)
__global__ __launch_bounds__(256) void convert_all(
    const float* __restrict__ x,
    const float* __restrict__ Wq, const float* __restrict__ Wk,
    const float* __restrict__ Wv, const float* __restrict__ Wo,
    ushort* __restrict__ xb, ushort* __restrict__ wb, int* __restrict__ deg)
{
    int i = blockIdx.x * 256 + threadIdx.x;   // pair index
    if (i < N_NODES) deg[i] = 0;
    int base = i * 2;
    if (base < NX) {
        float2 v = *reinterpret_cast<const float2*>(x + base);
        reinterpret_cast<uint*>(xb)[i] = pack2_bf16(v.x, v.y);
    } else {
        int j = base - NX;
        if (j < 4 * 16384) {
            const float* src = (j < 16384) ? Wq + j
                             : (j < 32768) ? Wk + (j - 16384)
                             : (j < 49152) ? Wv + (j - 32768)
                             :               Wo + (j - 49152);
            float2 v = *reinterpret_cast<const float2*>(src);
            reinterpret_cast<uint*>(wb)[j >> 1] = pack2_bf16(v.x, v.y);
        }
    }
}

// ---------------------------------------------------------------------------
// MFMA GEMM for Q/K/V + degree histogram (r8 grid structure).
// blockIdx.y in {0,1,2}: GEMM with weights/bias q/k/v; y==3: histogram.
// NEW: LDS-staged epilogue — wave writes its 16x128 bf16 tile into a private
// 4 KB LDS slab (ds_write_b16, wave-internal, no barrier), reads back uint4,
// stores 4 fully-coalesced 1-KB dwordx4 per wave instead of 32 scattered
// 2-byte stores (partial-line RMW was the suspected 50-us write-path cost).
// ---------------------------------------------------------------------------
__global__ __launch_bounds__(256) void gemm_qkv_deg(
    const ushort* __restrict__ A, const ushort* __restrict__ Wall,
    const float* __restrict__ bq, const float* __restrict__ bk,
    const float* __restrict__ bv,
    ushort* __restrict__ Qb, ushort* __restrict__ Kb, ushort* __restrict__ Vb,
    const int* __restrict__ ei, int* __restrict__ deg,
    int M)
{
    const int which = blockIdx.y;
    if (which == 3) {
        int t = blockIdx.x * 256 + threadIdx.x;
        int e = t * 4;
        if (e + 3 < N_EDGES) {
            int4 d = *reinterpret_cast<const int4*>(ei + e);
            atomicAdd(&deg[d.x], 1);
            atomicAdd(&deg[d.y], 1);
            atomicAdd(&deg[d.z], 1);
            atomicAdd(&deg[d.w], 1);
        } else {
            for (; e < N_EDGES && e < t * 4 + 4; ++e)
                atomicAdd(&deg[ei[e]], 1);
        }
        return;
    }

    __shared__ ushort cs[4][2048];   // 4 KB per wave

    const ushort* W = Wall + which * 16384;
    const float* bias = (which == 0) ? bq : (which == 1) ? bk : bv;
    ushort* C = (which == 0) ? Qb : (which == 1) ? Kb : Vb;

    const int lane = threadIdx.x & 63;
    const int wave = threadIdx.x >> 6;
    const int ml   = lane & 15;
    const int quad = lane >> 4;
    const int m0   = blockIdx.x * 64 + wave * 16;

    int arow = m0 + ml; if (arow >= M) arow = M - 1;
    const ushort* ap = A + arow * 128 + quad * 8;

    f32x4 acc[8];
#pragma unroll
    for (int ct = 0; ct < 8; ++ct) acc[ct] = (f32x4){0.f, 0.f, 0.f, 0.f};

#pragma unroll
    for (int ks = 0; ks < 128; ks += 32) {
        bf16x8 af = *reinterpret_cast<const bf16x8*>(ap + ks);
#pragma unroll
        for (int ct = 0; ct < 8; ++ct) {
            bf16x8 bf = *reinterpret_cast<const bf16x8*>(
                W + (ct * 16 + ml) * 128 + ks + quad * 8);
            acc[ct] = __builtin_amdgcn_mfma_f32_16x16x32_bf16(af, bf, acc[ct], 0, 0, 0);
        }
    }

    // stage tile in this wave's LDS slab (wave-internal ordering: no barrier)
    ushort* my = cs[wave];
#pragma unroll
    for (int ct = 0; ct < 8; ++ct) {
        int col = ct * 16 + ml;
        float bv_ = bias[col];
#pragma unroll
        for (int r = 0; r < 4; ++r)
            my[(quad * 4 + r) * 128 + col] = cvt_bf16(acc[ct][r] + bv_);
    }

    // wide coalesced stores: 4 x dwordx4 per lane covers 16x128 bf16
    const uint4* mv = reinterpret_cast<const uint4*>(my);
    uint4* Cv = reinterpret_cast<uint4*>(C + m0 * 128);
    int rem = M - m0;                         // rows available in this tile
#pragma unroll
    for (int it = 0; it < 4; ++it) {
        int c = it * 64 + lane;               // chunk 0..255, row = c>>4
        if ((c >> 4) < rem) Cv[c] = mv[c];
    }
}

// Final projection: A bf16 [M,128] @ W^T + bias -> fp32 out
__global__ __launch_bounds__(256) void gemm_out(
    const ushort* __restrict__ A, const ushort* __restrict__ W,
    const float* __restrict__ bias, float* __restrict__ C, int M)
{
    const int lane = threadIdx.x & 63;
    const int wave = threadIdx.x >> 6;
    const int ml   = lane & 15;
    const int quad = lane >> 4;
    const int m0   = blockIdx.x * 64 + wave * 16;

    int arow = m0 + ml; if (arow >= M) arow = M - 1;
    const ushort* ap = A + arow * 128 + quad * 8;

    f32x4 acc[8];
#pragma unroll
    for (int ct = 0; ct < 8; ++ct) acc[ct] = (f32x4){0.f, 0.f, 0.f, 0.f};

#pragma unroll
    for (int ks = 0; ks < 128; ks += 32) {
        bf16x8 af = *reinterpret_cast<const bf16x8*>(ap + ks);
#pragma unroll
        for (int ct = 0; ct < 8; ++ct) {
            bf16x8 bf = *reinterpret_cast<const bf16x8*>(
                W + (ct * 16 + ml) * 128 + ks + quad * 8);
            acc[ct] = __builtin_amdgcn_mfma_f32_16x16x32_bf16(af, bf, acc[ct], 0, 0, 0);
        }
    }

#pragma unroll
    for (int ct = 0; ct < 8; ++ct) {
        int col = ct * 16 + ml;
        float bv_ = bias[col];
#pragma unroll
        for (int r = 0; r < 4; ++r) {
            int row = m0 + quad * 4 + r;
            if (row < M)
                C[row * 128 + col] = acc[ct][r] + bv_;   // 64-B coalesced chunks
        }
    }
}

// ---------------------------------------------------------------------------
// Hierarchical exclusive scan (2 kernels) + scatter (int2 {e, src}).
// ---------------------------------------------------------------------------
__global__ __launch_bounds__(256) void scan_blocks(
    const int* __restrict__ deg, int* __restrict__ excl, int* __restrict__ bsum)
{
    __shared__ int sh[256];
    int t = threadIdx.x;
    int gid = blockIdx.x * 256 + t;
    int v = (gid < N_NODES) ? deg[gid] : 0;
    sh[t] = v;
    __syncthreads();
#pragma unroll
    for (int off = 1; off < 256; off <<= 1) {
        int u = (t >= off) ? sh[t - off] : 0;
        __syncthreads();
        sh[t] += u;
        __syncthreads();
    }
    if (gid < N_NODES) excl[gid] = sh[t] - v;
    if (t == 255) bsum[blockIdx.x] = sh[255];
}

__global__ __launch_bounds__(256) void scan_apply(
    int* __restrict__ excl, const int* __restrict__ bsum,
    int* __restrict__ cursor)
{
    __shared__ int base_sh;
    int t = threadIdx.x;
    if (t < 64) {
        int s = 0;
        for (int i = t; i < (int)blockIdx.x; i += 64) s += bsum[i];
#pragma unroll
        for (int off = 32; off; off >>= 1) s += __shfl_xor(s, off, 64);
        if (t == 0) base_sh = s;
    }
    __syncthreads();
    int gid = blockIdx.x * 256 + t;
    if (gid < N_NODES) {
        int o = excl[gid] + base_sh;
        excl[gid] = o;         // excl buffer IS offsets
        cursor[gid] = o;
    }
    if (blockIdx.x == 0 && t == 0) excl[N_NODES] = N_EDGES;
}

__global__ __launch_bounds__(256) void scatter_edges(
    const int* __restrict__ ei, int* __restrict__ cursor,
    int2* __restrict__ csr2)
{
    int e = blockIdx.x * 256 + threadIdx.x;
    if (e >= N_EDGES) return;
    int dst = ei[e];
    int src = ei[N_EDGES + e];
    int pos = atomicAdd(&cursor[dst], 1);
    csr2[pos] = make_int2(e, src);
}

// ---------------------------------------------------------------------------
// Fused attention v7 (r8-proven): one wave per node, one (edge, head) per
// lane. lane = e_slot*8 + h. Full 16-dim dot in registers; exp once per
// (e,h); reduce-scatter butterfly at the end. exp without max-subtraction.
// ---------------------------------------------------------------------------
__global__ __launch_bounds__(256) void fused_attn(
    const ushort* __restrict__ Q2, const ushort* __restrict__ K2,
    const ushort* __restrict__ V2,
    const float* __restrict__ attn_bias,
    const int* __restrict__ offsets, const int2* __restrict__ csr2,
    float* __restrict__ logits, ushort* __restrict__ AGG)
{
    const int lane = threadIdx.x & 63;
    const int wid  = threadIdx.x >> 6;
    const int n = blockIdx.x * 4 + wid;
    const int start = offsets[n], end = offsets[n + 1];
    const int h  = lane & 7;
    const int es = lane >> 3;

    const uint4* Qu4 = reinterpret_cast<const uint4*>(Q2);
    const uint4* Ku4 = reinterpret_cast<const uint4*>(K2);
    const uint4* Vu4 = reinterpret_cast<const uint4*>(V2);

    uint4 qa = Qu4[n * 16 + h * 2];
    uint4 qb = Qu4[n * 16 + h * 2 + 1];
    float qf[16];
    {
        uint qq[8] = {qa.x, qa.y, qa.z, qa.w, qb.x, qb.y, qb.z, qb.w};
#pragma unroll
        for (int j = 0; j < 8; ++j) {
            qf[2 * j]     = bf16_lo(qq[j]);
            qf[2 * j + 1] = bf16_hi(qq[j]);
        }
    }

    float acc[16];
#pragma unroll
    for (int j = 0; j < 16; ++j) acc[j] = 0.f;
    float z = 0.f;

    for (int base = start; base < end; base += 8) {
        bool valid = (base + es) < end;
        int idx = base + es; if (!valid) idx = end - 1;
        int2 epair = csr2[idx];
        int e = epair.x, s = epair.y;

        uint4 k0 = Ku4[s * 16 + h * 2];
        uint4 k1 = Ku4[s * 16 + h * 2 + 1];
        uint4 v0 = Vu4[s * 16 + h * 2];
        uint4 v1 = Vu4[s * 16 + h * 2 + 1];
        float bias = attn_bias[e * 8 + h];

        uint kk[8] = {k0.x, k0.y, k0.z, k0.w, k1.x, k1.y, k1.z, k1.w};
        float d = 0.f;
#pragma unroll
        for (int j = 0; j < 8; ++j)
            d += qf[2 * j] * bf16_lo(kk[j]) + qf[2 * j + 1] * bf16_hi(kk[j]);

        float l = 0.25f * d + bias;
        float p = 0.f;
        if (valid) {
            logits[e * 8 + h] = l;
            p = __expf(l);
        }
        z += p;

        uint vv[8] = {v0.x, v0.y, v0.z, v0.w, v1.x, v1.y, v1.z, v1.w};
#pragma unroll
        for (int j = 0; j < 8; ++j) {
            acc[2 * j]     += p * bf16_lo(vv[j]);
            acc[2 * j + 1] += p * bf16_hi(vv[j]);
        }
    }

    // reduce-scatter butterfly over e_slot bits (lane bits 5,4,3)
    {
        int bit = (lane >> 5) & 1;
#pragma unroll
        for (int j = 0; j < 8; ++j) {
            float send = bit ? acc[j] : acc[j + 8];
            float keep = bit ? acc[j + 8] : acc[j];
            acc[j] = keep + __shfl_xor(send, 32, 64);
        }
        bit = (lane >> 4) & 1;
#pragma unroll
        for (int j = 0; j < 4; ++j) {
            float send = bit ? acc[j] : acc[j + 4];
            float keep = bit ? acc[j + 4] : acc[j];
            acc[j] = keep + __shfl_xor(send, 16, 64);
        }
        bit = (lane >> 3) & 1;
#pragma unroll
        for (int j = 0; j < 2; ++j) {
            float send = bit ? acc[j] : acc[j + 2];
            float keep = bit ? acc[j + 2] : acc[j];
            acc[j] = keep + __shfl_xor(send, 8, 64);
        }
    }
    z += __shfl_xor(z, 8, 64);
    z += __shfl_xor(z, 16, 64);
    z += __shfl_xor(z, 32, 64);

    float inv = (z > 0.f) ? 1.f / z : 0.f;
    int d_off = ((lane >> 5) & 1) * 8 + ((lane >> 4) & 1) * 4 + ((lane >> 3) & 1) * 2;
    reinterpret_cast<uint*>(AGG)[n * 64 + h * 8 + (d_off >> 1)] =
        pack2_bf16(acc[0] * inv, acc[1] * inv);
}

// ---------------------------------------------------------------------------
extern "C" void kernel_launch(void* const* d_in, const int* in_sizes, int n_in,
                              void* d_out, int out_size, void* d_ws, size_t ws_size,
                              hipStream_t stream)
{
    const float* x         = (const float*)d_in[0];
    const int*   ei        = (const int*)  d_in[1];
    const float* attn_bias = (const float*)d_in[2];
    const float* Wq = (const float*)d_in[3];
    const float* bq = (const float*)d_in[4];
    const float* Wk = (const float*)d_in[5];
    const float* bk = (const float*)d_in[6];
    const float* Wv = (const float*)d_in[7];
    const float* bv = (const float*)d_in[8];
    const float* Wo = (const float*)d_in[9];
    const float* bo = (const float*)d_in[10];

    float* out    = (float*)d_out;                // [N,128]
    float* logits = out + N_NODES * EMBED;        // [E,8] (output 1)

    ushort* xb   = (ushort*)d_ws;                 // N*128
    ushort* wb   = xb + NX;                       // 4*16384 (Wq,Wk,Wv,Wo)
    ushort* Qb   = wb + 4 * 16384;                // N*128
    ushort* Kb   = Qb + NX;                       // N*128
    ushort* Vb   = Kb + NX;                       // N*128
    ushort* AGGb = Vb + NX;                       // N*128
    int* deg     = (int*)(AGGb + NX);
    int* offsets = deg + N_NODES;                 // N+1 (also excl buffer)
    int* cursor  = offsets + N_NODES + 1;
    int2* csr2   = (int2*)(cursor + N_NODES);     // E pairs {edge, src}
    int* bsum    = (int*)(csr2 + N_EDGES);        // NBLK

    int npairs = (NX + 4 * 16384) / 2;
    convert_all<<<(npairs + 255) / 256, 256, 0, stream>>>(x, Wq, Wk, Wv, Wo, xb, wb, deg);

    int gblocks = (N_NODES + 63) / 64;            // 391
    dim3 qkvgrid(gblocks, 4);                     // y=0..2 gemm, y=3 histogram
    gemm_qkv_deg<<<qkvgrid, 256, 0, stream>>>(xb, wb, bq, bk, bv, Qb, Kb, Vb,
                                              ei, deg, N_NODES);

    scan_blocks<<<NBLK, 256, 0, stream>>>(deg, offsets, bsum);
    scan_apply<<<NBLK, 256, 0, stream>>>(offsets, bsum, cursor);
    scatter_edges<<<(N_EDGES + 255) / 256, 256, 0, stream>>>(ei, cursor, csr2);

    fused_attn<<<N_NODES / 4, 256, 0, stream>>>(Qb, Kb, Vb, attn_bias,
                                                offsets, csr2, logits, AGGb);

    int gblocks2 = (N_NODES + 63) / 64;           // 391
    gemm_out<<<gblocks2, 256, 0, stream>>>(AGGb, wb + 3 * 16384, bo, out, N_NODES);
}